// Round 5
// baseline (203.916 us; speedup 1.0000x reference)
//
#include <hip/hip_runtime.h>
#include <math.h>

#define LN_EPS 1e-5f

typedef __attribute__((ext_vector_type(8))) short bf16x8;
typedef __attribute__((ext_vector_type(4))) float f32x4;
typedef unsigned short ushort_t;
typedef unsigned int uint_t;

__device__ __forceinline__ ushort_t f2bf(float f) {
    uint_t u = __float_as_uint(f);
    u += 0x7FFF + ((u >> 16) & 1);          // RNE
    return (ushort_t)(u >> 16);
}

// ---------------------------------------------------------------------------
// Prep: [0,3840) activations fp32->bf16 (flat, 4/thr)
//       [3840,5760) transpose-convert weights [K][512]f32 -> [512][K]bf16,
//                   W1 halves scaled by LN gamma (g_text / g_img) per k-row.
//       5760: zero stats buffer (3200 rows x {sum,sumsq}) + 32 agg counters.
//       [5761,5769): folded-vector partials gW/bW = coef^T @ W1half,
//                    4 k-chunks x {text,img}, stored as [vec][4][512].
// ---------------------------------------------------------------------------
__global__ __launch_bounds__(256) void prep_kernel(
    const float* __restrict__ text, const float* __restrict__ image,
    ushort_t* __restrict__ text_bf, ushort_t* __restrict__ image_bf,
    const float* __restrict__ W_text, const float* __restrict__ W_img,
    const float* __restrict__ W1,
    const float* __restrict__ g_text, const float* __restrict__ beta_text,
    const float* __restrict__ g_img, const float* __restrict__ beta_img,
    ushort_t* __restrict__ Wt_t, ushort_t* __restrict__ Wi_t,
    ushort_t* __restrict__ W1t_g, ushort_t* __restrict__ W1i_g,
    float* __restrict__ stats, float* __restrict__ vparts,
    uint_t* __restrict__ cnt)
{
    __shared__ float t[32][33];
    const int bid = blockIdx.x;
    const int tid = threadIdx.x;
    if (bid < 3840) {
        const int i4 = (bid * 256 + tid) * 4;
        const float* src; ushort_t* dst; int off;
        if (i4 < 1572864) { src = text;  dst = text_bf;  off = i4; }
        else              { src = image; dst = image_bf; off = i4 - 1572864; }
        float4 v = *(const float4*)(src + off);
        ushort4 o;
        o.x = f2bf(v.x); o.y = f2bf(v.y); o.z = f2bf(v.z); o.w = f2bf(v.w);
        *(ushort4*)(dst + off) = o;
        return;
    }
    int local = bid - 3840;
    if (local < 1920) {
        const float* src; ushort_t* dst; int K; const float* gs = nullptr;
        if      (local < 384)  { src = W_text;       dst = Wt_t;  K = 768;  }
        else if (local < 1408) { src = W_img;        dst = Wi_t;  K = 2048; local -= 384; }
        else if (local < 1664) { src = W1;           dst = W1t_g; K = 512;  local -= 1408; gs = g_text; }
        else                   { src = W1 + 512*512; dst = W1i_g; K = 512;  local -= 1664; gs = g_img; }
        const int ntk = K / 32;
        const int k0 = (local % ntk) * 32;
        const int n0 = (local / ntk) * 32;
        const int x = tid % 32, y = tid / 32;
        #pragma unroll
        for (int j = 0; j < 4; ++j)
            t[y + 8 * j][x] = src[(size_t)(k0 + y + 8 * j) * 512 + n0 + x];
        __syncthreads();
        const float gv = gs ? gs[k0 + x] : 1.f;
        #pragma unroll
        for (int j = 0; j < 4; ++j)
            dst[(size_t)(n0 + y + 8 * j) * K + k0 + x] = f2bf(t[x][y + 8 * j] * gv);
        return;
    }
    if (local == 1920) {                    // zero stats (6400 floats) + counters
        for (int i = tid; i < 6400; i += 256) stats[i] = 0.f;
        if (tid < 32) cnt[tid] = 0u;
        return;
    }
    // folded-vector partial blocks: j in [0,8)
    {
        const int j    = local - 1921;
        const int half = j >> 2;            // 0 = text (W1[:512]), 1 = image
        const int jj   = j & 3;             // k-chunk of 128
        const float* cg = half ? g_img : g_text;
        const float* cb = half ? beta_img : beta_text;
        const float* Wb = W1 + (size_t)(half * 512 + jj * 128) * 512;
        const int n = tid;
        float ag0 = 0.f, ab0 = 0.f, ag1 = 0.f, ab1 = 0.f;
        #pragma unroll 4
        for (int k = 0; k < 128; ++k) {
            const float c1 = cg[jj * 128 + k];
            const float c2 = cb[jj * 128 + k];
            const float w0 = Wb[(size_t)k * 512 + n];
            const float w1 = Wb[(size_t)k * 512 + n + 256];
            ag0 = fmaf(c1, w0, ag0); ab0 = fmaf(c2, w0, ab0);
            ag1 = fmaf(c1, w1, ag1); ab1 = fmaf(c2, w1, ab1);
        }
        float* vg = vparts + (size_t)(half * 2 + 0) * 2048 + jj * 512;
        float* vb = vparts + (size_t)(half * 2 + 1) * 2048 + jj * 512;
        vg[n] = ag0; vg[n + 256] = ag1;
        vb[n] = ab0; vb[n + 256] = ab1;
    }
}

// ---------------------------------------------------------------------------
// GEMM core: barrier-free split-K bf16 MFMA, C[64x64]/block, N=512.
// A[M][K], Bt[N][K] both K-contiguous bf16; fragments loaded directly from
// global (16x16x32 layout row=lane&15, k=(lane>>4)*8+j). 4 waves split K;
// one LDS reduction. Two problems per launch via blockIdx.y.
// ---------------------------------------------------------------------------
__device__ __forceinline__ void gemm_core(
    const ushort_t* __restrict__ A, const ushort_t* __restrict__ Bt, int K,
    int brow, int bcol, int wave, int lane, float (&red)[4][64][64])
{
    const int q  = lane >> 4;
    const int mj = lane & 15;
    const ushort_t* Ab = A  + (size_t)(brow + mj) * K + q * 8;
    const ushort_t* Bb = Bt + (size_t)(bcol + mj) * K + q * 8;
    const int kw0    = wave * (K >> 2);
    const int ksteps = K >> 7;

    f32x4 acc[4][4] = {};
    #pragma unroll 2
    for (int s = 0; s < ksteps; ++s) {
        const int k = kw0 + s * 32;
        bf16x8 af[4], bf[4];
        #pragma unroll
        for (int i = 0; i < 4; ++i) {
            af[i] = *(const bf16x8*)(Ab + (size_t)i * 16 * K + k);
            bf[i] = *(const bf16x8*)(Bb + (size_t)i * 16 * K + k);
        }
        #pragma unroll
        for (int mi = 0; mi < 4; ++mi)
            #pragma unroll
            for (int ni = 0; ni < 4; ++ni)
                acc[mi][ni] = __builtin_amdgcn_mfma_f32_16x16x32_bf16(
                    af[mi], bf[ni], acc[mi][ni], 0, 0, 0);
    }
    #pragma unroll
    for (int mi = 0; mi < 4; ++mi)
        #pragma unroll
        for (int ni = 0; ni < 4; ++ni)
            #pragma unroll
            for (int r = 0; r < 4; ++r)
                red[wave][mi * 16 + q * 4 + r][ni * 16 + mj] = acc[mi][ni][r];
    __syncthreads();
}

// gemm1 epilogue: +bias, relu, write raw bf16 (and fp32 if Cf), accumulate
// per-row {sum, sumsq} into stats via atomics (for the folded LayerNorm).
__global__ __launch_bounds__(256) void gemm1_kernel(
    const ushort_t* __restrict__ A0, const ushort_t* __restrict__ B0,
    const float* __restrict__ bias0, ushort_t* __restrict__ Cb0,
    float* __restrict__ Cf0, float* __restrict__ st0, int K0,
    const ushort_t* __restrict__ A1, const ushort_t* __restrict__ B1,
    const float* __restrict__ bias1, ushort_t* __restrict__ Cb1,
    float* __restrict__ Cf1, float* __restrict__ st1, int K1,
    int ysplit)
{
    __shared__ float red[4][64][64];
    const ushort_t* A; const ushort_t* Bt; const float* bias;
    ushort_t* Cb; float* Cf; float* st; int K;
    int yy = blockIdx.y;
    if (yy < ysplit) { A=A0; Bt=B0; bias=bias0; Cb=Cb0; Cf=Cf0; st=st0; K=K0; }
    else { A=A1; Bt=B1; bias=bias1; Cb=Cb1; Cf=Cf1; st=st1; K=K1; yy -= ysplit; }

    const int tid  = threadIdx.x;
    const int brow = yy * 64;
    const int bcol = blockIdx.x * 64;
    gemm_core(A, Bt, K, brow, bcol, tid >> 6, tid & 63, red);

    #pragma unroll
    for (int g = 0; g < 4; ++g) {
        const int idx = g * 1024 + tid * 4;
        const int row = idx >> 6, col = idx & 63;
        float4 v0 = *(float4*)&red[0][row][col];
        float4 v1 = *(float4*)&red[1][row][col];
        float4 v2 = *(float4*)&red[2][row][col];
        float4 v3 = *(float4*)&red[3][row][col];
        float4 o;
        o.x = (v0.x + v1.x) + (v2.x + v3.x);
        o.y = (v0.y + v1.y) + (v2.y + v3.y);
        o.z = (v0.z + v1.z) + (v2.z + v3.z);
        o.w = (v0.w + v1.w) + (v2.w + v3.w);
        float4 bv = *(const float4*)&bias[bcol + col];
        o.x = fmaxf(o.x + bv.x, 0.f); o.y = fmaxf(o.y + bv.y, 0.f);
        o.z = fmaxf(o.z + bv.z, 0.f); o.w = fmaxf(o.w + bv.w, 0.f);
        ushort4 ob;
        ob.x = f2bf(o.x); ob.y = f2bf(o.y); ob.z = f2bf(o.z); ob.w = f2bf(o.w);
        *(ushort4*)&Cb[(size_t)(brow + row) * 512 + bcol + col] = ob;
        if (Cf) *(float4*)&Cf[(size_t)(brow + row) * 512 + bcol + col] = o;
        float s1 = (o.x + o.y) + (o.z + o.w);
        float s2 = fmaf(o.x, o.x, fmaf(o.y, o.y, fmaf(o.z, o.z, o.w * o.w)));
        #pragma unroll
        for (int off = 8; off; off >>= 1) {
            s1 += __shfl_down(s1, off, 16);
            s2 += __shfl_down(s2, off, 16);
        }
        if ((tid & 15) == 0) {
            atomicAdd(&st[(size_t)(brow + row) * 2],     s1);
            atomicAdd(&st[(size_t)(brow + row) * 2 + 1], s2);
        }
    }
}

// gemm2: A is RAW relu'd bf16; epilogue applies folded LayerNorm:
//   h = rstd*acc - rstd*mu*gW[col] + bW[col] (+ b1 for image half)
__global__ __launch_bounds__(256) void gemm2_kernel(
    const ushort_t* __restrict__ A0, const ushort_t* __restrict__ B0,
    const float* __restrict__ bias0, float* __restrict__ C0,
    const float* __restrict__ st0, const float* __restrict__ gW0,
    const float* __restrict__ bW0, int K0,
    const ushort_t* __restrict__ A1, const ushort_t* __restrict__ B1,
    const float* __restrict__ bias1, float* __restrict__ C1,
    const float* __restrict__ st1, const float* __restrict__ gW1,
    const float* __restrict__ bW1, int K1,
    int ysplit)
{
    __shared__ float red[4][64][64];
    const ushort_t* A; const ushort_t* Bt; const float* bias; float* C;
    const float* st; const float* gW; const float* bW; int K;
    int yy = blockIdx.y;
    if (yy < ysplit) { A=A0; Bt=B0; bias=bias0; C=C0; st=st0; gW=gW0; bW=bW0; K=K0; }
    else { A=A1; Bt=B1; bias=bias1; C=C1; st=st1; gW=gW1; bW=bW1; K=K1; yy -= ysplit; }

    const int tid  = threadIdx.x;
    const int brow = yy * 64;
    const int bcol = blockIdx.x * 64;
    gemm_core(A, Bt, K, brow, bcol, tid >> 6, tid & 63, red);

    #pragma unroll
    for (int g = 0; g < 4; ++g) {
        const int idx = g * 1024 + tid * 4;
        const int row = idx >> 6, col = idx & 63;
        float4 v0 = *(float4*)&red[0][row][col];
        float4 v1 = *(float4*)&red[1][row][col];
        float4 v2 = *(float4*)&red[2][row][col];
        float4 v3 = *(float4*)&red[3][row][col];
        float4 s;
        s.x = (v0.x + v1.x) + (v2.x + v3.x);
        s.y = (v0.y + v1.y) + (v2.y + v3.y);
        s.z = (v0.z + v1.z) + (v2.z + v3.z);
        s.w = (v0.w + v1.w) + (v2.w + v3.w);
        const float st1v = st[(size_t)(brow + row) * 2];
        const float st2v = st[(size_t)(brow + row) * 2 + 1];
        const float mu   = st1v * (1.f / 512.f);
        const float var  = st2v * (1.f / 512.f) - mu * mu;
        const float rstd = rsqrtf(var + LN_EPS);
        const int c = bcol + col;
        float4 gw = *(const float4*)&gW[c];
        float4 bw = *(const float4*)&bW[c];
        #pragma unroll
        for (int j = 1; j < 4; ++j) {
            float4 gp = *(const float4*)&gW[j * 512 + c];
            float4 bp = *(const float4*)&bW[j * 512 + c];
            gw.x += gp.x; gw.y += gp.y; gw.z += gp.z; gw.w += gp.w;
            bw.x += bp.x; bw.y += bp.y; bw.z += bp.z; bw.w += bp.w;
        }
        const float rm = rstd * mu;
        float4 o;
        o.x = fmaf(rstd, s.x, fmaf(-rm, gw.x, bw.x));
        o.y = fmaf(rstd, s.y, fmaf(-rm, gw.y, bw.y));
        o.z = fmaf(rstd, s.z, fmaf(-rm, gw.z, bw.z));
        o.w = fmaf(rstd, s.w, fmaf(-rm, gw.w, bw.w));
        if (bias) {
            float4 bb = *(const float4*)&bias[c];
            o.x += bb.x; o.y += bb.y; o.z += bb.z; o.w += bb.w;
        }
        *(float4*)&C[(size_t)(brow + row) * 512 + c] = o;
    }
}

// ---------------------------------------------------------------------------
// scores[b,e,r] = sigmoid( sum_d relu(h_t[b,e,d] + h_i[b,r,d]) * W2[d] + b2 )
// One block per (b,e). After storing, blocks arrive at cnt[b]; the 64th
// block for each b performs the softmax+aggregation (folded image LN) —
// identical numerics to the former agg_kernel, deterministic. No spin.
// ---------------------------------------------------------------------------
__global__ __launch_bounds__(256) void scores_agg_kernel(
    const float* __restrict__ ht, const float* __restrict__ hi,
    const float* __restrict__ W2, const float* __restrict__ b2,
    float* __restrict__ scores,
    const float* __restrict__ img, const float* __restrict__ stats,
    const float* __restrict__ g_img, const float* __restrict__ beta_img,
    float* __restrict__ outAgg, uint_t* __restrict__ cnt)
{
    const int be   = blockIdx.x;
    const int b    = be >> 6;
    const int tid  = threadIdx.x;
    const int lane = tid & 63;
    const int wave = tid >> 6;

    float htv[8], w2v[8];
    const float* htp = ht + (size_t)be * 512;
    #pragma unroll
    for (int j = 0; j < 8; ++j) {
        htv[j] = htp[lane + 64 * j];
        w2v[j] = W2[lane + 64 * j];
    }
    const float bb = b2[0];
    const float* hib = hi + (size_t)b * 36 * 512;

    for (int r = wave; r < 36; r += 4) {
        const float* hir = hib + (size_t)r * 512;
        float acc = 0.f;
        #pragma unroll
        for (int j = 0; j < 8; ++j) {
            float h = fmaxf(htv[j] + hir[lane + 64 * j], 0.f);
            acc = fmaf(h, w2v[j], acc);
        }
        #pragma unroll
        for (int off = 32; off; off >>= 1) acc += __shfl_down(acc, off);
        if (lane == 0) {
            float sr = acc + bb;
            scores[(size_t)be * 36 + r] = 1.f / (1.f + expf(-sr));
        }
    }

    // ---- arrival; last block of this batch runs the aggregation ----------
    __shared__ uint_t done;
    __syncthreads();                        // all score stores complete (vmcnt drained)
    if (tid == 0) {
        __threadfence();                    // agent-scope release (L2 writeback)
        done = atomicAdd(&cnt[b], 1u);
    }
    __syncthreads();
    if (done != 63u) return;
    if (tid == 0) __threadfence();          // acquire side (cheap, 1 block)
    __syncthreads();

    __shared__ float part[4][36];
    __shared__ float sexp[36];
    __shared__ float inv_s;
    __shared__ float coef[36], cmu[36];

    const float* sc = scores + (size_t)b * 2304;
    const int e4 = tid >> 6;
    const int r  = tid & 63;
    if (r < 36) {
        float p = 0.f;
        #pragma unroll
        for (int e = 0; e < 16; ++e) p += expf(sc[(e * 4 + e4) * 36 + r]);
        part[e4][r] = p;
    }
    __syncthreads();
    if (tid < 36) sexp[tid] = part[0][tid] + part[1][tid] + part[2][tid] + part[3][tid];
    __syncthreads();
    if (tid < 64) {
        float v = (tid < 36) ? sexp[tid] : 0.f;
        #pragma unroll
        for (int off = 32; off; off >>= 1) v += __shfl_down(v, off);
        if (tid == 0) inv_s = 1.f / (v * 64.f);
    }
    __syncthreads();
    const float inv = inv_s;
    if (tid < 36) {
        const float s1 = stats[(size_t)(b * 36 + tid) * 2];
        const float s2 = stats[(size_t)(b * 36 + tid) * 2 + 1];
        const float mu   = s1 * (1.f / 512.f);
        const float var  = s2 * (1.f / 512.f) - mu * mu;
        const float rstd = rsqrtf(var + LN_EPS);
        const float c = sexp[tid] * inv * rstd;
        coef[tid] = c;
        cmu[tid]  = c * mu;
    }
    __syncthreads();
    float S1 = 0.f;
    #pragma unroll
    for (int rr = 0; rr < 36; ++rr) S1 += cmu[rr];
    const float S0 = 1.f / 64.f;            // sum_r W_r (softmax sums to 1)

    const float* ib = img + (size_t)b * 36 * 512;
    for (int d = tid; d < 512; d += 256) {
        float acc = 0.f;
        #pragma unroll
        for (int rr = 0; rr < 36; ++rr)
            acc = fmaf(coef[rr], ib[rr * 512 + d], acc);
        outAgg[(size_t)b * 512 + d] = fmaf(g_img[d], acc - S1, beta_img[d] * S0);
    }
}

// ---------------------------------------------------------------------------
extern "C" void kernel_launch(void* const* d_in, const int* in_sizes, int n_in,
                              void* d_out, int out_size, void* d_ws, size_t ws_size,
                              hipStream_t stream)
{
    const float* text      = (const float*)d_in[0];
    const float* image     = (const float*)d_in[1];
    const float* W_text    = (const float*)d_in[2];
    const float* b_text    = (const float*)d_in[3];
    const float* g_text    = (const float*)d_in[4];
    const float* beta_text = (const float*)d_in[5];
    const float* W_img     = (const float*)d_in[6];
    const float* b_img     = (const float*)d_in[7];
    const float* g_img     = (const float*)d_in[8];
    const float* beta_img  = (const float*)d_in[9];
    const float* W1        = (const float*)d_in[10];
    const float* b1        = (const float*)d_in[11];
    const float* W2        = (const float*)d_in[12];
    const float* b2        = (const float*)d_in[13];

    float* out_scores = (float*)d_out;            // 32*64*36
    float* out_agg    = (float*)d_out + 73728;    // 32*512

    char* ws = (char*)d_ws;
    ushort_t* ta_bf    = (ushort_t*)(ws);                       // 2 MB   raw relu'd text proj (bf16)
    ushort_t* ia_bf    = (ushort_t*)(ws + 2097152);             // 1.125 MB raw relu'd image proj (bf16)
    float*    ia       = (float*)(ws + 3276800);                // 2.25 MB raw relu'd image proj (fp32)
    float*    ht       = (float*)(ws + 5636096);                // 4 MB
    float*    hi       = (float*)(ws + 9830400);                // 2.25 MB
    ushort_t* text_bf  = (ushort_t*)(ws + 12189696);            // 3 MB
    ushort_t* image_bf = (ushort_t*)(ws + 15335424);            // 4.5 MB
    ushort_t* Wt_t     = (ushort_t*)(ws + 20054016);            // 0.75 MB
    ushort_t* Wi_t     = (ushort_t*)(ws + 20840448);            // 2 MB
    ushort_t* W1t_g    = (ushort_t*)(ws + 22937600);            // 0.5 MB (gamma-scaled)
    ushort_t* W1i_g    = (ushort_t*)(ws + 23461888);            // 0.5 MB (gamma-scaled)
    float*    stats    = (float*)(ws + 23986176);               // 3200 x {sum,sumsq}
    float*    vparts   = (float*)(ws + 24011776);               // 4 vecs x 4 parts x 512
    uint_t*   cnt      = (uint_t*)(ws + 24044544);              // 32 agg counters

    // 1) convert + transpose(+gamma-fold) + stats/cnt-zero + folded vectors
    prep_kernel<<<5769, 256, 0, stream>>>(
        text, image, text_bf, image_bf, W_text, W_img, W1,
        g_text, beta_text, g_img, beta_img,
        Wt_t, Wi_t, W1t_g, W1i_g, stats, vparts, cnt);
    // 2) both projections + bias + relu -> raw bf16 (+fp32 image) + row stats
    //    image (K=2048, long blocks) scheduled FIRST for better balance
    gemm1_kernel<<<dim3(8, 50), 256, 0, stream>>>(
        image_bf, Wi_t, b_img, ia_bf, ia, stats + 4096, 2048,
        text_bf, Wt_t, b_text, ta_bf, nullptr, stats, 768,
        18);
    // 3) h_t / h_i on raw bf16 with folded-LN epilogue (+b1 for image)
    gemm2_kernel<<<dim3(8, 50), 256, 0, stream>>>(
        ta_bf, W1t_g, nullptr, ht, stats,        vparts,        vparts + 2048, 512,
        ia_bf, W1i_g, b1,      hi, stats + 4096, vparts + 4096, vparts + 6144, 512,
        32);
    // 4) pair scores + sigmoid -> out[0]; last block per batch aggregates -> out[1]
    scores_agg_kernel<<<2048, 256, 0, stream>>>(
        ht, hi, W2, b2, out_scores,
        ia, stats + 4096, g_img, beta_img, out_agg, cnt);
}

// Round 6
// 155.213 us; speedup vs baseline: 1.3138x; 1.3138x over previous
//
#include <hip/hip_runtime.h>
#include <math.h>

#define LN_EPS 1e-5f

typedef __attribute__((ext_vector_type(8))) short bf16x8;
typedef __attribute__((ext_vector_type(4))) float f32x4;
typedef unsigned short ushort_t;
typedef unsigned int uint_t;

__device__ __forceinline__ ushort_t f2bf(float f) {
    uint_t u = __float_as_uint(f);
    u += 0x7FFF + ((u >> 16) & 1);          // RNE
    return (ushort_t)(u >> 16);
}

// ---------------------------------------------------------------------------
// Prep: [0,3840) activations fp32->bf16 (flat, 4/thr)
//       [3840,5760) transpose-convert weights [K][512]f32 -> [512][K]bf16,
//                   W1 halves scaled by LN gamma (g_text / g_img) per k-row.
//       5760: zero stats buffer (3200 rows x {sum,sumsq}).
//       [5761,5769): folded-vector partials gW/bW = coef^T @ W1half,
//                    4 k-chunks x {text,img}, stored as [vec][4][512].
// ---------------------------------------------------------------------------
__global__ __launch_bounds__(256) void prep_kernel(
    const float* __restrict__ text, const float* __restrict__ image,
    ushort_t* __restrict__ text_bf, ushort_t* __restrict__ image_bf,
    const float* __restrict__ W_text, const float* __restrict__ W_img,
    const float* __restrict__ W1,
    const float* __restrict__ g_text, const float* __restrict__ beta_text,
    const float* __restrict__ g_img, const float* __restrict__ beta_img,
    ushort_t* __restrict__ Wt_t, ushort_t* __restrict__ Wi_t,
    ushort_t* __restrict__ W1t_g, ushort_t* __restrict__ W1i_g,
    float* __restrict__ stats, float* __restrict__ vparts)
{
    __shared__ float t[32][33];
    const int bid = blockIdx.x;
    const int tid = threadIdx.x;
    if (bid < 3840) {
        const int i4 = (bid * 256 + tid) * 4;
        const float* src; ushort_t* dst; int off;
        if (i4 < 1572864) { src = text;  dst = text_bf;  off = i4; }
        else              { src = image; dst = image_bf; off = i4 - 1572864; }
        float4 v = *(const float4*)(src + off);
        ushort4 o;
        o.x = f2bf(v.x); o.y = f2bf(v.y); o.z = f2bf(v.z); o.w = f2bf(v.w);
        *(ushort4*)(dst + off) = o;
        return;
    }
    int local = bid - 3840;
    if (local < 1920) {
        const float* src; ushort_t* dst; int K; const float* gs = nullptr;
        if      (local < 384)  { src = W_text;       dst = Wt_t;  K = 768;  }
        else if (local < 1408) { src = W_img;        dst = Wi_t;  K = 2048; local -= 384; }
        else if (local < 1664) { src = W1;           dst = W1t_g; K = 512;  local -= 1408; gs = g_text; }
        else                   { src = W1 + 512*512; dst = W1i_g; K = 512;  local -= 1664; gs = g_img; }
        const int ntk = K / 32;
        const int k0 = (local % ntk) * 32;
        const int n0 = (local / ntk) * 32;
        const int x = tid % 32, y = tid / 32;
        #pragma unroll
        for (int j = 0; j < 4; ++j)
            t[y + 8 * j][x] = src[(size_t)(k0 + y + 8 * j) * 512 + n0 + x];
        __syncthreads();
        const float gv = gs ? gs[k0 + x] : 1.f;
        #pragma unroll
        for (int j = 0; j < 4; ++j)
            dst[(size_t)(n0 + y + 8 * j) * K + k0 + x] = f2bf(t[x][y + 8 * j] * gv);
        return;
    }
    if (local == 1920) {                    // zero stats (6400 floats)
        for (int i = tid; i < 6400; i += 256) stats[i] = 0.f;
        return;
    }
    // folded-vector partial blocks: j in [0,8)
    {
        const int j    = local - 1921;
        const int half = j >> 2;            // 0 = text (W1[:512]), 1 = image
        const int jj   = j & 3;             // k-chunk of 128
        const float* cg = half ? g_img : g_text;
        const float* cb = half ? beta_img : beta_text;
        const float* Wb = W1 + (size_t)(half * 512 + jj * 128) * 512;
        const int n = tid;
        float ag0 = 0.f, ab0 = 0.f, ag1 = 0.f, ab1 = 0.f;
        #pragma unroll 4
        for (int k = 0; k < 128; ++k) {
            const float c1 = cg[jj * 128 + k];
            const float c2 = cb[jj * 128 + k];
            const float w0 = Wb[(size_t)k * 512 + n];
            const float w1 = Wb[(size_t)k * 512 + n + 256];
            ag0 = fmaf(c1, w0, ag0); ab0 = fmaf(c2, w0, ab0);
            ag1 = fmaf(c1, w1, ag1); ab1 = fmaf(c2, w1, ab1);
        }
        float* vg = vparts + (size_t)(half * 2 + 0) * 2048 + jj * 512;
        float* vb = vparts + (size_t)(half * 2 + 1) * 2048 + jj * 512;
        vg[n] = ag0; vg[n + 256] = ag1;
        vb[n] = ab0; vb[n + 256] = ab1;
    }
}

// ---------------------------------------------------------------------------
// GEMM core: barrier-free split-K bf16 MFMA, C[64x64]/block, N=512.
// A[M][K], Bt[N][K] both K-contiguous bf16; fragments loaded directly from
// global (16x16x32 layout row=lane&15, k=(lane>>4)*8+j). 4 waves split K;
// one LDS reduction. Two problems per launch via blockIdx.y.
// ---------------------------------------------------------------------------
__device__ __forceinline__ void gemm_core(
    const ushort_t* __restrict__ A, const ushort_t* __restrict__ Bt, int K,
    int brow, int bcol, int wave, int lane, float (&red)[4][64][64])
{
    const int q  = lane >> 4;
    const int mj = lane & 15;
    const ushort_t* Ab = A  + (size_t)(brow + mj) * K + q * 8;
    const ushort_t* Bb = Bt + (size_t)(bcol + mj) * K + q * 8;
    const int kw0    = wave * (K >> 2);
    const int ksteps = K >> 7;

    f32x4 acc[4][4] = {};
    #pragma unroll 2
    for (int s = 0; s < ksteps; ++s) {
        const int k = kw0 + s * 32;
        bf16x8 af[4], bf[4];
        #pragma unroll
        for (int i = 0; i < 4; ++i) {
            af[i] = *(const bf16x8*)(Ab + (size_t)i * 16 * K + k);
            bf[i] = *(const bf16x8*)(Bb + (size_t)i * 16 * K + k);
        }
        #pragma unroll
        for (int mi = 0; mi < 4; ++mi)
            #pragma unroll
            for (int ni = 0; ni < 4; ++ni)
                acc[mi][ni] = __builtin_amdgcn_mfma_f32_16x16x32_bf16(
                    af[mi], bf[ni], acc[mi][ni], 0, 0, 0);
    }
    #pragma unroll
    for (int mi = 0; mi < 4; ++mi)
        #pragma unroll
        for (int ni = 0; ni < 4; ++ni)
            #pragma unroll
            for (int r = 0; r < 4; ++r)
                red[wave][mi * 16 + q * 4 + r][ni * 16 + mj] = acc[mi][ni][r];
    __syncthreads();
}

// gemm1 epilogue: +bias, relu, write raw bf16 (and fp32 if Cf), accumulate
// per-row {sum, sumsq} into stats via atomics (for the folded LayerNorm).
__global__ __launch_bounds__(256) void gemm1_kernel(
    const ushort_t* __restrict__ A0, const ushort_t* __restrict__ B0,
    const float* __restrict__ bias0, ushort_t* __restrict__ Cb0,
    float* __restrict__ Cf0, float* __restrict__ st0, int K0,
    const ushort_t* __restrict__ A1, const ushort_t* __restrict__ B1,
    const float* __restrict__ bias1, ushort_t* __restrict__ Cb1,
    float* __restrict__ Cf1, float* __restrict__ st1, int K1,
    int ysplit)
{
    __shared__ float red[4][64][64];
    const ushort_t* A; const ushort_t* Bt; const float* bias;
    ushort_t* Cb; float* Cf; float* st; int K;
    int yy = blockIdx.y;
    if (yy < ysplit) { A=A0; Bt=B0; bias=bias0; Cb=Cb0; Cf=Cf0; st=st0; K=K0; }
    else { A=A1; Bt=B1; bias=bias1; Cb=Cb1; Cf=Cf1; st=st1; K=K1; yy -= ysplit; }

    const int tid  = threadIdx.x;
    const int brow = yy * 64;
    const int bcol = blockIdx.x * 64;
    gemm_core(A, Bt, K, brow, bcol, tid >> 6, tid & 63, red);

    #pragma unroll
    for (int g = 0; g < 4; ++g) {
        const int idx = g * 1024 + tid * 4;
        const int row = idx >> 6, col = idx & 63;
        float4 v0 = *(float4*)&red[0][row][col];
        float4 v1 = *(float4*)&red[1][row][col];
        float4 v2 = *(float4*)&red[2][row][col];
        float4 v3 = *(float4*)&red[3][row][col];
        float4 o;
        o.x = (v0.x + v1.x) + (v2.x + v3.x);
        o.y = (v0.y + v1.y) + (v2.y + v3.y);
        o.z = (v0.z + v1.z) + (v2.z + v3.z);
        o.w = (v0.w + v1.w) + (v2.w + v3.w);
        float4 bv = *(const float4*)&bias[bcol + col];
        o.x = fmaxf(o.x + bv.x, 0.f); o.y = fmaxf(o.y + bv.y, 0.f);
        o.z = fmaxf(o.z + bv.z, 0.f); o.w = fmaxf(o.w + bv.w, 0.f);
        ushort4 ob;
        ob.x = f2bf(o.x); ob.y = f2bf(o.y); ob.z = f2bf(o.z); ob.w = f2bf(o.w);
        *(ushort4*)&Cb[(size_t)(brow + row) * 512 + bcol + col] = ob;
        if (Cf) *(float4*)&Cf[(size_t)(brow + row) * 512 + bcol + col] = o;
        float s1 = (o.x + o.y) + (o.z + o.w);
        float s2 = fmaf(o.x, o.x, fmaf(o.y, o.y, fmaf(o.z, o.z, o.w * o.w)));
        #pragma unroll
        for (int off = 8; off; off >>= 1) {
            s1 += __shfl_down(s1, off, 16);
            s2 += __shfl_down(s2, off, 16);
        }
        if ((tid & 15) == 0) {
            atomicAdd(&st[(size_t)(brow + row) * 2],     s1);
            atomicAdd(&st[(size_t)(brow + row) * 2 + 1], s2);
        }
    }
}

// gemm2: A is RAW relu'd bf16; epilogue applies folded LayerNorm:
//   h = rstd*acc - rstd*mu*gW[col] + bW[col] (+ b1 for image half)
__global__ __launch_bounds__(256) void gemm2_kernel(
    const ushort_t* __restrict__ A0, const ushort_t* __restrict__ B0,
    const float* __restrict__ bias0, float* __restrict__ C0,
    const float* __restrict__ st0, const float* __restrict__ gW0,
    const float* __restrict__ bW0, int K0,
    const ushort_t* __restrict__ A1, const ushort_t* __restrict__ B1,
    const float* __restrict__ bias1, float* __restrict__ C1,
    const float* __restrict__ st1, const float* __restrict__ gW1,
    const float* __restrict__ bW1, int K1,
    int ysplit)
{
    __shared__ float red[4][64][64];
    const ushort_t* A; const ushort_t* Bt; const float* bias; float* C;
    const float* st; const float* gW; const float* bW; int K;
    int yy = blockIdx.y;
    if (yy < ysplit) { A=A0; Bt=B0; bias=bias0; C=C0; st=st0; gW=gW0; bW=bW0; K=K0; }
    else { A=A1; Bt=B1; bias=bias1; C=C1; st=st1; gW=gW1; bW=bW1; K=K1; yy -= ysplit; }

    const int tid  = threadIdx.x;
    const int brow = yy * 64;
    const int bcol = blockIdx.x * 64;
    gemm_core(A, Bt, K, brow, bcol, tid >> 6, tid & 63, red);

    #pragma unroll
    for (int g = 0; g < 4; ++g) {
        const int idx = g * 1024 + tid * 4;
        const int row = idx >> 6, col = idx & 63;
        float4 v0 = *(float4*)&red[0][row][col];
        float4 v1 = *(float4*)&red[1][row][col];
        float4 v2 = *(float4*)&red[2][row][col];
        float4 v3 = *(float4*)&red[3][row][col];
        float4 s;
        s.x = (v0.x + v1.x) + (v2.x + v3.x);
        s.y = (v0.y + v1.y) + (v2.y + v3.y);
        s.z = (v0.z + v1.z) + (v2.z + v3.z);
        s.w = (v0.w + v1.w) + (v2.w + v3.w);
        const float st1v = st[(size_t)(brow + row) * 2];
        const float st2v = st[(size_t)(brow + row) * 2 + 1];
        const float mu   = st1v * (1.f / 512.f);
        const float var  = st2v * (1.f / 512.f) - mu * mu;
        const float rstd = rsqrtf(var + LN_EPS);
        const int c = bcol + col;
        float4 gw = *(const float4*)&gW[c];
        float4 bw = *(const float4*)&bW[c];
        #pragma unroll
        for (int j = 1; j < 4; ++j) {
            float4 gp = *(const float4*)&gW[j * 512 + c];
            float4 bp = *(const float4*)&bW[j * 512 + c];
            gw.x += gp.x; gw.y += gp.y; gw.z += gp.z; gw.w += gp.w;
            bw.x += bp.x; bw.y += bp.y; bw.z += bp.z; bw.w += bp.w;
        }
        const float rm = rstd * mu;
        float4 o;
        o.x = fmaf(rstd, s.x, fmaf(-rm, gw.x, bw.x));
        o.y = fmaf(rstd, s.y, fmaf(-rm, gw.y, bw.y));
        o.z = fmaf(rstd, s.z, fmaf(-rm, gw.z, bw.z));
        o.w = fmaf(rstd, s.w, fmaf(-rm, gw.w, bw.w));
        if (bias) {
            float4 bb = *(const float4*)&bias[c];
            o.x += bb.x; o.y += bb.y; o.z += bb.z; o.w += bb.w;
        }
        *(float4*)&C[(size_t)(brow + row) * 512 + c] = o;
    }
}

// ---------------------------------------------------------------------------
// scores[b,e,r] = sigmoid( sum_d relu(h_t[b,e,d] + h_i[b,r,d]) * W2[d] + b2 )
// One block per (b,e); wave w owns r = w + 4k, k=0..8. ILP restructure: all
// nine accumulators live simultaneously so the 72 hi-loads pipeline across
// iterations instead of stalling once per r; butterfly reduces batched at
// the end (independent chains).
// ---------------------------------------------------------------------------
__global__ __launch_bounds__(256) void scores_kernel(
    const float* __restrict__ ht, const float* __restrict__ hi,
    const float* __restrict__ W2, const float* __restrict__ b2,
    float* __restrict__ scores)
{
    const int be   = blockIdx.x;
    const int b    = be >> 6;
    const int tid  = threadIdx.x;
    const int lane = tid & 63;
    const int wave = tid >> 6;

    float htv[8], w2v[8];
    const float* htp = ht + (size_t)be * 512;
    #pragma unroll
    for (int j = 0; j < 8; ++j) {
        htv[j] = htp[lane + 64 * j];
        w2v[j] = W2[lane + 64 * j];
    }
    const float bb = b2[0];
    const float* hib = hi + (size_t)b * 36 * 512 + wave * 512;

    float acc[9];
    #pragma unroll
    for (int k = 0; k < 9; ++k) acc[k] = 0.f;
    #pragma unroll
    for (int k = 0; k < 9; ++k) {
        const float* hir = hib + (size_t)k * 2048;      // r = wave + 4k
        #pragma unroll
        for (int j = 0; j < 8; ++j) {
            float h = fmaxf(htv[j] + hir[lane + 64 * j], 0.f);
            acc[k] = fmaf(h, w2v[j], acc[k]);
        }
    }
    #pragma unroll
    for (int off = 32; off; off >>= 1)
        #pragma unroll
        for (int k = 0; k < 9; ++k)
            acc[k] += __shfl_down(acc[k], off);
    if (lane == 0) {
        #pragma unroll
        for (int k = 0; k < 9; ++k)
            scores[(size_t)be * 36 + wave + 4 * k] =
                1.f / (1.f + expf(-(acc[k] + bb)));
    }
}

// ---------------------------------------------------------------------------
// Softmax + aggregation with folded image LayerNorm:
//   out_d = g_d * (sum_r coef_r * x[r,d] - S1) + beta_d/64
//   coef_r = W_r * rstd_r,  S1 = sum_r coef_r * mu_r,  W_r = sexp_r * inv.
// ---------------------------------------------------------------------------
__global__ __launch_bounds__(256) void agg_kernel(
    const float* __restrict__ scores, const float* __restrict__ img,
    const float* __restrict__ stats, const float* __restrict__ g_img,
    const float* __restrict__ beta_img, float* __restrict__ outAgg)
{
    const int b   = blockIdx.x;
    const int tid = threadIdx.x;
    const float* sc = scores + (size_t)b * 2304;

    __shared__ float part[4][36];
    __shared__ float sexp[36];
    __shared__ float inv_s;
    __shared__ float coef[36], cmu[36];

    const int e4 = tid >> 6;
    const int r  = tid & 63;
    if (r < 36) {
        float p = 0.f;
        #pragma unroll
        for (int e = 0; e < 16; ++e) p += expf(sc[(e * 4 + e4) * 36 + r]);
        part[e4][r] = p;
    }
    __syncthreads();
    if (tid < 36) sexp[tid] = part[0][tid] + part[1][tid] + part[2][tid] + part[3][tid];
    __syncthreads();
    if (tid < 64) {
        float v = (tid < 36) ? sexp[tid] : 0.f;
        #pragma unroll
        for (int off = 32; off; off >>= 1) v += __shfl_down(v, off);
        if (tid == 0) inv_s = 1.f / (v * 64.f);
    }
    __syncthreads();
    const float inv = inv_s;
    if (tid < 36) {
        const float s1 = stats[(size_t)(b * 36 + tid) * 2];
        const float s2 = stats[(size_t)(b * 36 + tid) * 2 + 1];
        const float mu   = s1 * (1.f / 512.f);
        const float var  = s2 * (1.f / 512.f) - mu * mu;
        const float rstd = rsqrtf(var + LN_EPS);
        const float c = sexp[tid] * inv * rstd;
        coef[tid] = c;
        cmu[tid]  = c * mu;
    }
    __syncthreads();
    float S1 = 0.f;
    #pragma unroll
    for (int rr = 0; rr < 36; ++rr) S1 += cmu[rr];
    const float S0 = 1.f / 64.f;            // sum_r W_r (softmax sums to 1)

    const float* ib = img + (size_t)b * 36 * 512;
    for (int d = tid; d < 512; d += 256) {
        float acc = 0.f;
        #pragma unroll
        for (int rr = 0; rr < 36; ++rr)
            acc = fmaf(coef[rr], ib[rr * 512 + d], acc);
        outAgg[(size_t)b * 512 + d] = fmaf(g_img[d], acc - S1, beta_img[d] * S0);
    }
}

// ---------------------------------------------------------------------------
extern "C" void kernel_launch(void* const* d_in, const int* in_sizes, int n_in,
                              void* d_out, int out_size, void* d_ws, size_t ws_size,
                              hipStream_t stream)
{
    const float* text      = (const float*)d_in[0];
    const float* image     = (const float*)d_in[1];
    const float* W_text    = (const float*)d_in[2];
    const float* b_text    = (const float*)d_in[3];
    const float* g_text    = (const float*)d_in[4];
    const float* beta_text = (const float*)d_in[5];
    const float* W_img     = (const float*)d_in[6];
    const float* b_img     = (const float*)d_in[7];
    const float* g_img     = (const float*)d_in[8];
    const float* beta_img  = (const float*)d_in[9];
    const float* W1        = (const float*)d_in[10];
    const float* b1        = (const float*)d_in[11];
    const float* W2        = (const float*)d_in[12];
    const float* b2        = (const float*)d_in[13];

    float* out_scores = (float*)d_out;            // 32*64*36
    float* out_agg    = (float*)d_out + 73728;    // 32*512

    char* ws = (char*)d_ws;
    ushort_t* ta_bf    = (ushort_t*)(ws);                       // 2 MB   raw relu'd text proj (bf16)
    ushort_t* ia_bf    = (ushort_t*)(ws + 2097152);             // 1.125 MB raw relu'd image proj (bf16)
    float*    ia       = (float*)(ws + 3276800);                // 2.25 MB raw relu'd image proj (fp32)
    float*    ht       = (float*)(ws + 5636096);                // 4 MB
    float*    hi       = (float*)(ws + 9830400);                // 2.25 MB
    ushort_t* text_bf  = (ushort_t*)(ws + 12189696);            // 3 MB
    ushort_t* image_bf = (ushort_t*)(ws + 15335424);            // 4.5 MB
    ushort_t* Wt_t     = (ushort_t*)(ws + 20054016);            // 0.75 MB
    ushort_t* Wi_t     = (ushort_t*)(ws + 20840448);            // 2 MB
    ushort_t* W1t_g    = (ushort_t*)(ws + 22937600);            // 0.5 MB (gamma-scaled)
    ushort_t* W1i_g    = (ushort_t*)(ws + 23461888);            // 0.5 MB (gamma-scaled)
    float*    stats    = (float*)(ws + 23986176);               // 3200 x {sum,sumsq}
    float*    vparts   = (float*)(ws + 24011776);               // 4 vecs x 4 parts x 512

    // 1) convert + transpose(+gamma-fold) + stats-zero + folded vectors
    prep_kernel<<<5769, 256, 0, stream>>>(
        text, image, text_bf, image_bf, W_text, W_img, W1,
        g_text, beta_text, g_img, beta_img,
        Wt_t, Wi_t, W1t_g, W1i_g, stats, vparts);
    // 2) both projections + bias + relu -> raw bf16 (+fp32 image) + row stats
    //    image (K=2048, long blocks) scheduled FIRST for better balance
    gemm1_kernel<<<dim3(8, 50), 256, 0, stream>>>(
        image_bf, Wi_t, b_img, ia_bf, ia, stats + 4096, 2048,
        text_bf, Wt_t, b_text, ta_bf, nullptr, stats, 768,
        18);
    // 3) h_t / h_i on raw bf16 with folded-LN epilogue (+b1 for image)
    gemm2_kernel<<<dim3(8, 50), 256, 0, stream>>>(
        ta_bf, W1t_g, nullptr, ht, stats,        vparts,        vparts + 2048, 512,
        ia_bf, W1i_g, b1,      hi, stats + 4096, vparts + 4096, vparts + 6144, 512,
        32);
    // 4) pair scores + sigmoid -> out[0]
    scores_kernel<<<2048, 256, 0, stream>>>(ht, hi, W2, b2, out_scores);
    // 5) softmax + aggregation with folded image LN -> out[1]
    agg_kernel<<<32, 256, 0, stream>>>(out_scores, ia, stats + 4096,
                                       g_img, beta_img, out_agg);
}

// Round 7
// 154.321 us; speedup vs baseline: 1.3214x; 1.0058x over previous
//
#include <hip/hip_runtime.h>
#include <math.h>

#define LN_EPS 1e-5f

typedef __attribute__((ext_vector_type(8))) short bf16x8;
typedef __attribute__((ext_vector_type(4))) float f32x4;
typedef unsigned short ushort_t;
typedef unsigned int uint_t;

__device__ __forceinline__ ushort_t f2bf(float f) {
    uint_t u = __float_as_uint(f);
    u += 0x7FFF + ((u >> 16) & 1);          // RNE
    return (ushort_t)(u >> 16);
}

// ---------------------------------------------------------------------------
// Prep: [0,3840) activations fp32->bf16 (flat, 4/thr)
//       [3840,5760) transpose-convert weights [K][512]f32 -> [512][K]bf16,
//                   W1 halves scaled by LN gamma (g_text / g_img) per k-row.
//       5760: zero stats buffer (3200 rows x {sum,sumsq}).
//       [5761,5769): folded-vector partials gW/bW = coef^T @ W1half,
//                    4 k-chunks x {text,img}, stored as [vec][4][512].
// ---------------------------------------------------------------------------
__global__ __launch_bounds__(256) void prep_kernel(
    const float* __restrict__ text, const float* __restrict__ image,
    ushort_t* __restrict__ text_bf, ushort_t* __restrict__ image_bf,
    const float* __restrict__ W_text, const float* __restrict__ W_img,
    const float* __restrict__ W1,
    const float* __restrict__ g_text, const float* __restrict__ beta_text,
    const float* __restrict__ g_img, const float* __restrict__ beta_img,
    ushort_t* __restrict__ Wt_t, ushort_t* __restrict__ Wi_t,
    ushort_t* __restrict__ W1t_g, ushort_t* __restrict__ W1i_g,
    float* __restrict__ stats, float* __restrict__ vparts)
{
    __shared__ float t[32][33];
    const int bid = blockIdx.x;
    const int tid = threadIdx.x;
    if (bid < 3840) {
        const int i4 = (bid * 256 + tid) * 4;
        const float* src; ushort_t* dst; int off;
        if (i4 < 1572864) { src = text;  dst = text_bf;  off = i4; }
        else              { src = image; dst = image_bf; off = i4 - 1572864; }
        float4 v = *(const float4*)(src + off);
        ushort4 o;
        o.x = f2bf(v.x); o.y = f2bf(v.y); o.z = f2bf(v.z); o.w = f2bf(v.w);
        *(ushort4*)(dst + off) = o;
        return;
    }
    int local = bid - 3840;
    if (local < 1920) {
        const float* src; ushort_t* dst; int K; const float* gs = nullptr;
        if      (local < 384)  { src = W_text;       dst = Wt_t;  K = 768;  }
        else if (local < 1408) { src = W_img;        dst = Wi_t;  K = 2048; local -= 384; }
        else if (local < 1664) { src = W1;           dst = W1t_g; K = 512;  local -= 1408; gs = g_text; }
        else                   { src = W1 + 512*512; dst = W1i_g; K = 512;  local -= 1664; gs = g_img; }
        const int ntk = K / 32;
        const int k0 = (local % ntk) * 32;
        const int n0 = (local / ntk) * 32;
        const int x = tid % 32, y = tid / 32;
        #pragma unroll
        for (int j = 0; j < 4; ++j)
            t[y + 8 * j][x] = src[(size_t)(k0 + y + 8 * j) * 512 + n0 + x];
        __syncthreads();
        const float gv = gs ? gs[k0 + x] : 1.f;
        #pragma unroll
        for (int j = 0; j < 4; ++j)
            dst[(size_t)(n0 + y + 8 * j) * K + k0 + x] = f2bf(t[x][y + 8 * j] * gv);
        return;
    }
    if (local == 1920) {                    // zero stats (6400 floats)
        for (int i = tid; i < 6400; i += 256) stats[i] = 0.f;
        return;
    }
    // folded-vector partial blocks: j in [0,8)
    {
        const int j    = local - 1921;
        const int half = j >> 2;            // 0 = text (W1[:512]), 1 = image
        const int jj   = j & 3;             // k-chunk of 128
        const float* cg = half ? g_img : g_text;
        const float* cb = half ? beta_img : beta_text;
        const float* Wb = W1 + (size_t)(half * 512 + jj * 128) * 512;
        const int n = tid;
        float ag0 = 0.f, ab0 = 0.f, ag1 = 0.f, ab1 = 0.f;
        #pragma unroll 4
        for (int k = 0; k < 128; ++k) {
            const float c1 = cg[jj * 128 + k];
            const float c2 = cb[jj * 128 + k];
            const float w0 = Wb[(size_t)k * 512 + n];
            const float w1 = Wb[(size_t)k * 512 + n + 256];
            ag0 = fmaf(c1, w0, ag0); ab0 = fmaf(c2, w0, ab0);
            ag1 = fmaf(c1, w1, ag1); ab1 = fmaf(c2, w1, ab1);
        }
        float* vg = vparts + (size_t)(half * 2 + 0) * 2048 + jj * 512;
        float* vb = vparts + (size_t)(half * 2 + 1) * 2048 + jj * 512;
        vg[n] = ag0; vg[n + 256] = ag1;
        vb[n] = ab0; vb[n + 256] = ab1;
    }
}

// ---------------------------------------------------------------------------
// GEMM core: barrier-free split-K bf16 MFMA, C[64x64]/block, N=512.
// A[M][K], Bt[N][K] both K-contiguous bf16; fragments loaded directly from
// global (16x16x32 layout row=lane&15, k=(lane>>4)*8+j). 4 waves split K;
// one LDS reduction. Two problems per launch via blockIdx.y.
// ---------------------------------------------------------------------------
__device__ __forceinline__ void gemm_core(
    const ushort_t* __restrict__ A, const ushort_t* __restrict__ Bt, int K,
    int brow, int bcol, int wave, int lane, float (&red)[4][64][64])
{
    const int q  = lane >> 4;
    const int mj = lane & 15;
    const ushort_t* Ab = A  + (size_t)(brow + mj) * K + q * 8;
    const ushort_t* Bb = Bt + (size_t)(bcol + mj) * K + q * 8;
    const int kw0    = wave * (K >> 2);
    const int ksteps = K >> 7;

    f32x4 acc[4][4] = {};
    #pragma unroll 2
    for (int s = 0; s < ksteps; ++s) {
        const int k = kw0 + s * 32;
        bf16x8 af[4], bf[4];
        #pragma unroll
        for (int i = 0; i < 4; ++i) {
            af[i] = *(const bf16x8*)(Ab + (size_t)i * 16 * K + k);
            bf[i] = *(const bf16x8*)(Bb + (size_t)i * 16 * K + k);
        }
        #pragma unroll
        for (int mi = 0; mi < 4; ++mi)
            #pragma unroll
            for (int ni = 0; ni < 4; ++ni)
                acc[mi][ni] = __builtin_amdgcn_mfma_f32_16x16x32_bf16(
                    af[mi], bf[ni], acc[mi][ni], 0, 0, 0);
    }
    #pragma unroll
    for (int mi = 0; mi < 4; ++mi)
        #pragma unroll
        for (int ni = 0; ni < 4; ++ni)
            #pragma unroll
            for (int r = 0; r < 4; ++r)
                red[wave][mi * 16 + q * 4 + r][ni * 16 + mj] = acc[mi][ni][r];
    __syncthreads();
}

// gemm1 epilogue: +bias, relu, write raw bf16 (and fp32 if Cf), accumulate
// per-row {sum, sumsq} into stats via atomics (for the folded LayerNorm).
__global__ __launch_bounds__(256) void gemm1_kernel(
    const ushort_t* __restrict__ A0, const ushort_t* __restrict__ B0,
    const float* __restrict__ bias0, ushort_t* __restrict__ Cb0,
    float* __restrict__ Cf0, float* __restrict__ st0, int K0,
    const ushort_t* __restrict__ A1, const ushort_t* __restrict__ B1,
    const float* __restrict__ bias1, ushort_t* __restrict__ Cb1,
    float* __restrict__ Cf1, float* __restrict__ st1, int K1,
    int ysplit)
{
    __shared__ float red[4][64][64];
    const ushort_t* A; const ushort_t* Bt; const float* bias;
    ushort_t* Cb; float* Cf; float* st; int K;
    int yy = blockIdx.y;
    if (yy < ysplit) { A=A0; Bt=B0; bias=bias0; Cb=Cb0; Cf=Cf0; st=st0; K=K0; }
    else { A=A1; Bt=B1; bias=bias1; Cb=Cb1; Cf=Cf1; st=st1; K=K1; yy -= ysplit; }

    const int tid  = threadIdx.x;
    const int brow = yy * 64;
    const int bcol = blockIdx.x * 64;
    gemm_core(A, Bt, K, brow, bcol, tid >> 6, tid & 63, red);

    #pragma unroll
    for (int g = 0; g < 4; ++g) {
        const int idx = g * 1024 + tid * 4;
        const int row = idx >> 6, col = idx & 63;
        float4 v0 = *(float4*)&red[0][row][col];
        float4 v1 = *(float4*)&red[1][row][col];
        float4 v2 = *(float4*)&red[2][row][col];
        float4 v3 = *(float4*)&red[3][row][col];
        float4 o;
        o.x = (v0.x + v1.x) + (v2.x + v3.x);
        o.y = (v0.y + v1.y) + (v2.y + v3.y);
        o.z = (v0.z + v1.z) + (v2.z + v3.z);
        o.w = (v0.w + v1.w) + (v2.w + v3.w);
        float4 bv = *(const float4*)&bias[bcol + col];
        o.x = fmaxf(o.x + bv.x, 0.f); o.y = fmaxf(o.y + bv.y, 0.f);
        o.z = fmaxf(o.z + bv.z, 0.f); o.w = fmaxf(o.w + bv.w, 0.f);
        ushort4 ob;
        ob.x = f2bf(o.x); ob.y = f2bf(o.y); ob.z = f2bf(o.z); ob.w = f2bf(o.w);
        *(ushort4*)&Cb[(size_t)(brow + row) * 512 + bcol + col] = ob;
        if (Cf) *(float4*)&Cf[(size_t)(brow + row) * 512 + bcol + col] = o;
        float s1 = (o.x + o.y) + (o.z + o.w);
        float s2 = fmaf(o.x, o.x, fmaf(o.y, o.y, fmaf(o.z, o.z, o.w * o.w)));
        #pragma unroll
        for (int off = 8; off; off >>= 1) {
            s1 += __shfl_down(s1, off, 16);
            s2 += __shfl_down(s2, off, 16);
        }
        if ((tid & 15) == 0) {
            atomicAdd(&st[(size_t)(brow + row) * 2],     s1);
            atomicAdd(&st[(size_t)(brow + row) * 2 + 1], s2);
        }
    }
}

// gemm2: A is RAW relu'd bf16; epilogue applies folded LayerNorm:
//   h = rstd*acc - rstd*mu*gW[col] + bW[col] (+ b1 for image half)
__global__ __launch_bounds__(256) void gemm2_kernel(
    const ushort_t* __restrict__ A0, const ushort_t* __restrict__ B0,
    const float* __restrict__ bias0, float* __restrict__ C0,
    const float* __restrict__ st0, const float* __restrict__ gW0,
    const float* __restrict__ bW0, int K0,
    const ushort_t* __restrict__ A1, const ushort_t* __restrict__ B1,
    const float* __restrict__ bias1, float* __restrict__ C1,
    const float* __restrict__ st1, const float* __restrict__ gW1,
    const float* __restrict__ bW1, int K1,
    int ysplit)
{
    __shared__ float red[4][64][64];
    const ushort_t* A; const ushort_t* Bt; const float* bias; float* C;
    const float* st; const float* gW; const float* bW; int K;
    int yy = blockIdx.y;
    if (yy < ysplit) { A=A0; Bt=B0; bias=bias0; C=C0; st=st0; gW=gW0; bW=bW0; K=K0; }
    else { A=A1; Bt=B1; bias=bias1; C=C1; st=st1; gW=gW1; bW=bW1; K=K1; yy -= ysplit; }

    const int tid  = threadIdx.x;
    const int brow = yy * 64;
    const int bcol = blockIdx.x * 64;
    gemm_core(A, Bt, K, brow, bcol, tid >> 6, tid & 63, red);

    #pragma unroll
    for (int g = 0; g < 4; ++g) {
        const int idx = g * 1024 + tid * 4;
        const int row = idx >> 6, col = idx & 63;
        float4 v0 = *(float4*)&red[0][row][col];
        float4 v1 = *(float4*)&red[1][row][col];
        float4 v2 = *(float4*)&red[2][row][col];
        float4 v3 = *(float4*)&red[3][row][col];
        float4 s;
        s.x = (v0.x + v1.x) + (v2.x + v3.x);
        s.y = (v0.y + v1.y) + (v2.y + v3.y);
        s.z = (v0.z + v1.z) + (v2.z + v3.z);
        s.w = (v0.w + v1.w) + (v2.w + v3.w);
        const float st1v = st[(size_t)(brow + row) * 2];
        const float st2v = st[(size_t)(brow + row) * 2 + 1];
        const float mu   = st1v * (1.f / 512.f);
        const float var  = st2v * (1.f / 512.f) - mu * mu;
        const float rstd = rsqrtf(var + LN_EPS);
        const int c = bcol + col;
        float4 gw = *(const float4*)&gW[c];
        float4 bw = *(const float4*)&bW[c];
        #pragma unroll
        for (int j = 1; j < 4; ++j) {
            float4 gp = *(const float4*)&gW[j * 512 + c];
            float4 bp = *(const float4*)&bW[j * 512 + c];
            gw.x += gp.x; gw.y += gp.y; gw.z += gp.z; gw.w += gp.w;
            bw.x += bp.x; bw.y += bp.y; bw.z += bp.z; bw.w += bp.w;
        }
        const float rm = rstd * mu;
        float4 o;
        o.x = fmaf(rstd, s.x, fmaf(-rm, gw.x, bw.x));
        o.y = fmaf(rstd, s.y, fmaf(-rm, gw.y, bw.y));
        o.z = fmaf(rstd, s.z, fmaf(-rm, gw.z, bw.z));
        o.w = fmaf(rstd, s.w, fmaf(-rm, gw.w, bw.w));
        if (bias) {
            float4 bb = *(const float4*)&bias[c];
            o.x += bb.x; o.y += bb.y; o.z += bb.z; o.w += bb.w;
        }
        *(float4*)&C[(size_t)(brow + row) * 512 + c] = o;
    }
}

// ---------------------------------------------------------------------------
// scores[b,e,r] = sigmoid( sum_d relu(h_t[b,e,d] + h_i[b,r,d]) * W2[d] + b2 )
// One block per (b,e); wave w owns r = w + 4k, k=0..8. float4 loads
// (16 B/lane, G13) + 9 independent accumulators so the 18 VMEM ops pipeline;
// 9 butterfly reductions batched at the end.
// ---------------------------------------------------------------------------
__global__ __launch_bounds__(256) void scores_kernel(
    const float* __restrict__ ht, const float* __restrict__ hi,
    const float* __restrict__ W2, const float* __restrict__ b2,
    float* __restrict__ scores)
{
    const int be   = blockIdx.x;
    const int b    = be >> 6;
    const int tid  = threadIdx.x;
    const int lane = tid & 63;
    const int wave = tid >> 6;

    const float4* ht4 = (const float4*)(ht + (size_t)be * 512);
    const float4* W24 = (const float4*)W2;
    const float4 ha = ht4[lane],      hb = ht4[lane + 64];
    const float4 wa = W24[lane],      wb = W24[lane + 64];
    const float bb = b2[0];
    // row r = wave + 4k; rows are 128 float4 apart
    const float4* hi4 = (const float4*)(hi + (size_t)b * 36 * 512) + wave * 128;

    float acc[9];
    #pragma unroll
    for (int k = 0; k < 9; ++k) {
        const float4* hr = hi4 + (size_t)k * 512;       // 4 rows = 512 float4
        const float4 va = hr[lane];
        const float4 vb = hr[lane + 64];
        float a = 0.f;
        a = fmaf(fmaxf(ha.x + va.x, 0.f), wa.x, a);
        a = fmaf(fmaxf(ha.y + va.y, 0.f), wa.y, a);
        a = fmaf(fmaxf(ha.z + va.z, 0.f), wa.z, a);
        a = fmaf(fmaxf(ha.w + va.w, 0.f), wa.w, a);
        a = fmaf(fmaxf(hb.x + vb.x, 0.f), wb.x, a);
        a = fmaf(fmaxf(hb.y + vb.y, 0.f), wb.y, a);
        a = fmaf(fmaxf(hb.z + vb.z, 0.f), wb.z, a);
        a = fmaf(fmaxf(hb.w + vb.w, 0.f), wb.w, a);
        acc[k] = a;
    }
    #pragma unroll
    for (int off = 32; off; off >>= 1)
        #pragma unroll
        for (int k = 0; k < 9; ++k)
            acc[k] += __shfl_down(acc[k], off);
    if (lane == 0) {
        #pragma unroll
        for (int k = 0; k < 9; ++k)
            scores[(size_t)be * 36 + wave + 4 * k] =
                1.f / (1.f + expf(-(acc[k] + bb)));
    }
}

// ---------------------------------------------------------------------------
// Softmax + aggregation with folded image LayerNorm:
//   out_d = g_d * (sum_r coef_r * x[r,d] - S1) + beta_d/64
//   coef_r = W_r * rstd_r,  S1 = sum_r coef_r * mu_r,  W_r = sexp_r * inv.
// ---------------------------------------------------------------------------
__global__ __launch_bounds__(256) void agg_kernel(
    const float* __restrict__ scores, const float* __restrict__ img,
    const float* __restrict__ stats, const float* __restrict__ g_img,
    const float* __restrict__ beta_img, float* __restrict__ outAgg)
{
    const int b   = blockIdx.x;
    const int tid = threadIdx.x;
    const float* sc = scores + (size_t)b * 2304;

    __shared__ float part[4][36];
    __shared__ float sexp[36];
    __shared__ float inv_s;
    __shared__ float coef[36], cmu[36];

    const int e4 = tid >> 6;
    const int r  = tid & 63;
    if (r < 36) {
        float p = 0.f;
        #pragma unroll
        for (int e = 0; e < 16; ++e) p += expf(sc[(e * 4 + e4) * 36 + r]);
        part[e4][r] = p;
    }
    __syncthreads();
    if (tid < 36) sexp[tid] = part[0][tid] + part[1][tid] + part[2][tid] + part[3][tid];
    __syncthreads();
    if (tid < 64) {
        float v = (tid < 36) ? sexp[tid] : 0.f;
        #pragma unroll
        for (int off = 32; off; off >>= 1) v += __shfl_down(v, off);
        if (tid == 0) inv_s = 1.f / (v * 64.f);
    }
    __syncthreads();
    const float inv = inv_s;
    if (tid < 36) {
        const float s1 = stats[(size_t)(b * 36 + tid) * 2];
        const float s2 = stats[(size_t)(b * 36 + tid) * 2 + 1];
        const float mu   = s1 * (1.f / 512.f);
        const float var  = s2 * (1.f / 512.f) - mu * mu;
        const float rstd = rsqrtf(var + LN_EPS);
        const float c = sexp[tid] * inv * rstd;
        coef[tid] = c;
        cmu[tid]  = c * mu;
    }
    __syncthreads();
    float S1 = 0.f;
    #pragma unroll
    for (int rr = 0; rr < 36; ++rr) S1 += cmu[rr];
    const float S0 = 1.f / 64.f;            // sum_r W_r (softmax sums to 1)

    const float* ib = img + (size_t)b * 36 * 512;
    for (int d = tid; d < 512; d += 256) {
        float acc = 0.f;
        #pragma unroll
        for (int rr = 0; rr < 36; ++rr)
            acc = fmaf(coef[rr], ib[rr * 512 + d], acc);
        outAgg[(size_t)b * 512 + d] = fmaf(g_img[d], acc - S1, beta_img[d] * S0);
    }
}

// ---------------------------------------------------------------------------
extern "C" void kernel_launch(void* const* d_in, const int* in_sizes, int n_in,
                              void* d_out, int out_size, void* d_ws, size_t ws_size,
                              hipStream_t stream)
{
    const float* text      = (const float*)d_in[0];
    const float* image     = (const float*)d_in[1];
    const float* W_text    = (const float*)d_in[2];
    const float* b_text    = (const float*)d_in[3];
    const float* g_text    = (const float*)d_in[4];
    const float* beta_text = (const float*)d_in[5];
    const float* W_img     = (const float*)d_in[6];
    const float* b_img     = (const float*)d_in[7];
    const float* g_img     = (const float*)d_in[8];
    const float* beta_img  = (const float*)d_in[9];
    const float* W1        = (const float*)d_in[10];
    const float* b1        = (const float*)d_in[11];
    const float* W2        = (const float*)d_in[12];
    const float* b2        = (const float*)d_in[13];

    float* out_scores = (float*)d_out;            // 32*64*36
    float* out_agg    = (float*)d_out + 73728;    // 32*512

    char* ws = (char*)d_ws;
    ushort_t* ta_bf    = (ushort_t*)(ws);                       // 2 MB   raw relu'd text proj (bf16)
    ushort_t* ia_bf    = (ushort_t*)(ws + 2097152);             // 1.125 MB raw relu'd image proj (bf16)
    float*    ia       = (float*)(ws + 3276800);                // 2.25 MB raw relu'd image proj (fp32)
    float*    ht       = (float*)(ws + 5636096);                // 4 MB
    float*    hi       = (float*)(ws + 9830400);                // 2.25 MB
    ushort_t* text_bf  = (ushort_t*)(ws + 12189696);            // 3 MB
    ushort_t* image_bf = (ushort_t*)(ws + 15335424);            // 4.5 MB
    ushort_t* Wt_t     = (ushort_t*)(ws + 20054016);            // 0.75 MB
    ushort_t* Wi_t     = (ushort_t*)(ws + 20840448);            // 2 MB
    ushort_t* W1t_g    = (ushort_t*)(ws + 22937600);            // 0.5 MB (gamma-scaled)
    ushort_t* W1i_g    = (ushort_t*)(ws + 23461888);            // 0.5 MB (gamma-scaled)
    float*    stats    = (float*)(ws + 23986176);               // 3200 x {sum,sumsq}
    float*    vparts   = (float*)(ws + 24011776);               // 4 vecs x 4 parts x 512

    // 1) convert + transpose(+gamma-fold) + stats-zero + folded vectors
    prep_kernel<<<5769, 256, 0, stream>>>(
        text, image, text_bf, image_bf, W_text, W_img, W1,
        g_text, beta_text, g_img, beta_img,
        Wt_t, Wi_t, W1t_g, W1i_g, stats, vparts);
    // 2) both projections + bias + relu -> raw bf16 (+fp32 image) + row stats
    //    image (K=2048, long blocks) scheduled FIRST for better balance
    gemm1_kernel<<<dim3(8, 50), 256, 0, stream>>>(
        image_bf, Wi_t, b_img, ia_bf, ia, stats + 4096, 2048,
        text_bf, Wt_t, b_text, ta_bf, nullptr, stats, 768,
        18);
    // 3) h_t / h_i on raw bf16 with folded-LN epilogue (+b1 for image)
    gemm2_kernel<<<dim3(8, 50), 256, 0, stream>>>(
        ta_bf, W1t_g, nullptr, ht, stats,        vparts,        vparts + 2048, 512,
        ia_bf, W1i_g, b1,      hi, stats + 4096, vparts + 4096, vparts + 6144, 512,
        32);
    // 4) pair scores + sigmoid -> out[0]
    scores_kernel<<<2048, 256, 0, stream>>>(ht, hi, W2, b2, out_scores);
    // 5) softmax + aggregation with folded image LN -> out[1]
    agg_kernel<<<32, 256, 0, stream>>>(out_scores, ia, stats + 4096,
                                       g_img, beta_img, out_agg);
}